// Round 1
// baseline (736.502 us; speedup 1.0000x reference)
//
#include <hip/hip_runtime.h>
#include <hip/hip_bf16.h>
#include <stdint.h>

#define DEV static __device__ __forceinline__

typedef __attribute__((ext_vector_type(8))) short bf16x8;
typedef __attribute__((ext_vector_type(4))) short bf16x4;
typedef __attribute__((ext_vector_type(4))) float f32x4;

constexpr int Bc = 2, Sc = 2048, Dc = 2048;
constexpr int Hc = 16, HKVc = 4;
constexpr int RQc = 1024, RKVc = 512;
constexpr int DHc = 192, DRc = 64, DVc = 128;

DEV unsigned short f2bf(float f) {
  union { float f; uint32_t u; } v; v.f = f;
  uint32_t r = v.u + 0x7FFFu + ((v.u >> 16) & 1u);
  return (unsigned short)(r >> 16);
}
DEV float bf2f(unsigned short u) {
  union { uint32_t u; float f; } v; v.u = ((uint32_t)u) << 16;
  return v.f;
}

// ---------------- f32 -> bf16 conversion (vectorized) ----------------
__global__ void f2b_kernel(const float* __restrict__ in, unsigned short* __restrict__ out, int n) {
  int stride = gridDim.x * blockDim.x;
  for (int i = blockIdx.x * blockDim.x + threadIdx.x; i * 4 < n; i += stride) {
    float4 v = reinterpret_cast<const float4*>(in)[i];
    union { unsigned short u[4]; uint64_t q; } pk;
    pk.u[0] = f2bf(v.x); pk.u[1] = f2bf(v.y); pk.u[2] = f2bf(v.z); pk.u[3] = f2bf(v.w);
    reinterpret_cast<uint64_t*>(out)[i] = pk.q;
  }
}

// ---------------- RoPE cos/sin table ----------------
__global__ void rope_table_kernel(float* __restrict__ cosT, float* __restrict__ sinT) {
  int idx = blockIdx.x * blockDim.x + threadIdx.x;
  if (idx >= Sc * DRc) return;
  int t = idx >> 6;
  int j = idx & 63;
  // inv_freq = 10000^(-(j%32)/32)
  float inv = exp2f(-13.287712379549449f * (float)(j & 31) * (1.0f / 32.0f));
  float f = (float)t * inv;
  cosT[idx] = cosf(f);
  sinT[idx] = sinf(f);
}

// ---------------- RMSNorm (block per row), f32 in -> bf16 out ----------------
template<int R>
__global__ void rmsnorm_kernel(const float* __restrict__ in, int istride,
                               const float* __restrict__ g, unsigned short* __restrict__ out) {
  int row = blockIdx.x;
  const float* x = in + (size_t)row * istride;
  float ss = 0.f;
  for (int j = threadIdx.x; j < R; j += 256) { float v = x[j]; ss += v * v; }
  for (int off = 32; off; off >>= 1) ss += __shfl_down(ss, off, 64);
  __shared__ float wsum[4];
  if ((threadIdx.x & 63) == 0) wsum[threadIdx.x >> 6] = ss;
  __syncthreads();
  float tot = wsum[0] + wsum[1] + wsum[2] + wsum[3];
  float rs = rsqrtf(tot * (1.0f / R) + 1e-20f);
  for (int j = threadIdx.x; j < R; j += 256)
    out[(size_t)row * R + j] = f2bf(x[j] * rs * g[j]);
}

// ---------------- GEMM: C[M,N] = A[M,K](bf16) @ B[K,N](bf16) + bias ----------------
// 128x128 tile, BK=64, 4 waves (2x2), 16x16x32 bf16 MFMA.
// A staged row-major padded; B staged transposed (n-major, k-contiguous) so both
// fragment reads are contiguous b128.
template<bool OUT_BF16, bool NG>
__global__ __launch_bounds__(256)
void gemm_kernel(const unsigned short* __restrict__ A, const unsigned short* __restrict__ Bw,
                 const float* __restrict__ bias, void* __restrict__ Cout,
                 int M, int N, int K) {
  constexpr int BK = 64;
  __shared__ __align__(16) unsigned short As[128][72];
  __shared__ __align__(16) unsigned short Bt[128][72];
  const int t = threadIdx.x;
  const int lane = t & 63;
  const int wave = t >> 6;
  const int wm = wave >> 1, wn = wave & 1;
  const int m0 = blockIdx.y * 128, n0 = blockIdx.x * 128;
  const int fr = lane & 15, fo = (lane >> 4) * 8, rg = lane >> 4;

  const int a_row = t >> 1, a_cg = (t & 1) * 32;
  const int b_n = (t & 15) * 8;   // n offset within tile (octet)
  const int b_kq = (t >> 4);      // k quad index [0,16)
  const bool bok = !NG || (n0 + b_n + 8 <= N);

  f32x4 acc[4][4] = {};

  bf16x8 av[4], bv[4];
  auto load_tile = [&](int k0) {
    const unsigned short* ap = A + (size_t)(m0 + a_row) * K + k0 + a_cg;
    av[0] = *reinterpret_cast<const bf16x8*>(ap);
    av[1] = *reinterpret_cast<const bf16x8*>(ap + 8);
    av[2] = *reinterpret_cast<const bf16x8*>(ap + 16);
    av[3] = *reinterpret_cast<const bf16x8*>(ap + 24);
    if (bok) {
      const unsigned short* bp = Bw + (size_t)(k0 + b_kq * 4) * N + n0 + b_n;
      bv[0] = *reinterpret_cast<const bf16x8*>(bp);
      bv[1] = *reinterpret_cast<const bf16x8*>(bp + N);
      bv[2] = *reinterpret_cast<const bf16x8*>(bp + 2 * N);
      bv[3] = *reinterpret_cast<const bf16x8*>(bp + 3 * N);
    } else {
      bf16x8 z = {0, 0, 0, 0, 0, 0, 0, 0};
      bv[0] = z; bv[1] = z; bv[2] = z; bv[3] = z;
    }
  };

  load_tile(0);
  for (int k0 = 0; k0 < K; k0 += BK) {
    __syncthreads();
    *reinterpret_cast<bf16x8*>(&As[a_row][a_cg]) = av[0];
    *reinterpret_cast<bf16x8*>(&As[a_row][a_cg + 8]) = av[1];
    *reinterpret_cast<bf16x8*>(&As[a_row][a_cg + 16]) = av[2];
    *reinterpret_cast<bf16x8*>(&As[a_row][a_cg + 24]) = av[3];
#pragma unroll
    for (int j = 0; j < 8; ++j) {
      bf16x4 w = { bv[0][j], bv[1][j], bv[2][j], bv[3][j] };
      *reinterpret_cast<bf16x4*>(&Bt[b_n + j][b_kq * 4]) = w;
    }
    __syncthreads();
    if (k0 + BK < K) load_tile(k0 + BK);  // prefetch next tile under compute
#pragma unroll
    for (int kk = 0; kk < BK; kk += 32) {
      bf16x8 af[4], bfr[4];
#pragma unroll
      for (int m = 0; m < 4; ++m)
        af[m] = *reinterpret_cast<const bf16x8*>(&As[wm * 64 + m * 16 + fr][kk + fo]);
#pragma unroll
      for (int n = 0; n < 4; ++n)
        bfr[n] = *reinterpret_cast<const bf16x8*>(&Bt[wn * 64 + n * 16 + fr][kk + fo]);
#pragma unroll
      for (int m = 0; m < 4; ++m)
#pragma unroll
        for (int n = 0; n < 4; ++n)
          acc[m][n] = __builtin_amdgcn_mfma_f32_16x16x32_bf16(af[m], bfr[n], acc[m][n], 0, 0, 0);
    }
  }
#pragma unroll
  for (int m = 0; m < 4; ++m) {
    const int row = m0 + wm * 64 + m * 16 + rg * 4;
#pragma unroll
    for (int n = 0; n < 4; ++n) {
      const int col = n0 + wn * 64 + n * 16 + fr;
      if (NG && col >= N) continue;
      const float bb = bias[col];
#pragma unroll
      for (int r = 0; r < 4; ++r) {
        float v = acc[m][n][r] + bb;
        if (OUT_BF16)
          reinterpret_cast<unsigned short*>(Cout)[(size_t)(row + r) * N + col] = f2bf(v);
        else
          reinterpret_cast<float*>(Cout)[(size_t)(row + r) * N + col] = v;
      }
    }
  }
}

// ---------------- prep Q: q_b[4096,3072](bf16) -> Q[B,H,S,192], rope on last 64 ----------------
__global__ void prep_q_kernel(const unsigned short* __restrict__ qb,
                              const float* __restrict__ cosT, const float* __restrict__ sinT,
                              unsigned short* __restrict__ Q) {
  int bs = blockIdx.x;
  int s = bs & (Sc - 1);
  int b = bs >> 11;
  int d = threadIdx.x;
  if (d >= 192) return;
  for (int h = 0; h < Hc; ++h) {
    const unsigned short* src = qb + (size_t)bs * (Hc * DHc) + h * DHc;
    unsigned short o;
    if (d < 128) {
      o = src[d];
    } else {
      int j = d - 128;
      float x = bf2f(src[128 + j]);
      float other = bf2f(src[128 + (j < 32 ? j + 32 : j - 32)]);
      float c = cosT[s * 64 + j], sn = sinT[s * 64 + j];
      float v = (j < 32) ? (x * c - other * sn) : (x * c + other * sn);
      o = f2bf(v);
    }
    Q[(((size_t)(b * Hc + h)) * Sc + s) * DHc + d] = o;
  }
}

// ---------------- prep K: kv_b(bf16) nrope + kv_a(f32) rope -> K[B,HKV,S,192] ----------------
__global__ void prep_k_kernel(const unsigned short* __restrict__ kvb,
                              const float* __restrict__ kva,
                              const float* __restrict__ cosT, const float* __restrict__ sinT,
                              unsigned short* __restrict__ K) {
  int bs = blockIdx.x;
  int s = bs & (Sc - 1);
  int b = bs >> 11;
  int d = threadIdx.x;
  if (d >= 192) return;
  unsigned short ropeval = 0;
  if (d >= 128) {
    int j = d - 128;
    float x = kva[(size_t)bs * 576 + 512 + j];
    float other = kva[(size_t)bs * 576 + 512 + (j < 32 ? j + 32 : j - 32)];
    float c = cosT[s * 64 + j], sn = sinT[s * 64 + j];
    float v = (j < 32) ? (x * c - other * sn) : (x * c + other * sn);
    ropeval = f2bf(v);
  }
  for (int kvh = 0; kvh < HKVc; ++kvh) {
    unsigned short o;
    if (d < 128) o = kvb[(size_t)bs * 1024 + kvh * 256 + d];
    else o = ropeval;
    K[(((size_t)(b * HKVc + kvh)) * Sc + s) * DHc + d] = o;
  }
}

// ---------------- V transpose: kv_b[...,128:256] -> Vt[B,HKV,128,S] ----------------
__global__ void vtrans_kernel(const unsigned short* __restrict__ kvb, unsigned short* __restrict__ Vt) {
  int idx = blockIdx.x;
  int dt = idx & 3;  idx >>= 2;   // DV/32
  int st = idx & 63; idx >>= 6;   // S/32
  int kvh = idx & 3; idx >>= 2;
  int b = idx;
  __shared__ unsigned short tile[32][33];
  int t = threadIdx.x;
  int c = t & 31, r0 = t >> 5;
#pragma unroll
  for (int i = 0; i < 4; ++i) {
    int r = r0 + i * 8;
    int s = st * 32 + r;
    tile[r][c] = kvb[((size_t)(b * Sc + s)) * 1024 + kvh * 256 + 128 + dt * 32 + c];
  }
  __syncthreads();
#pragma unroll
  for (int i = 0; i < 4; ++i) {
    int r = r0 + i * 8;
    Vt[((size_t)((b * HKVc + kvh) * DVc + dt * 32 + r)) * Sc + st * 32 + c] = tile[c][r];
  }
}

// ---------------- flash attention ----------------
// grid (B*H, S/64); 4 waves, each owns 16 q rows; per-wave causal kv loop (no block barriers).
__global__ __launch_bounds__(256)
void attn_kernel(const unsigned short* __restrict__ Q, const unsigned short* __restrict__ Kt,
                 const unsigned short* __restrict__ Vt, unsigned short* __restrict__ attnOut) {
  const int bh = blockIdx.x;
  const int qt = blockIdx.y;
  const int b = bh >> 4, h = bh & 15;
  const int kvh = h >> 2;
  const int wave = threadIdx.x >> 6, lane = threadIdx.x & 63;
  const int q0 = qt * 64 + wave * 16;
  const int fr = lane & 15, fo = (lane >> 4) * 8, rg = lane >> 4;

  __shared__ __align__(16) unsigned short P_lds[4][16][40];

  const unsigned short* Qb = Q + (((size_t)(b * Hc + h)) * Sc + q0) * DHc;
  const unsigned short* Kb = Kt + (((size_t)(b * HKVc + kvh)) * Sc) * DHc;
  const unsigned short* Vb = Vt + (((size_t)(b * HKVc + kvh)) * DVc) * Sc;

  bf16x8 qf[6];
#pragma unroll
  for (int kd = 0; kd < 6; ++kd)
    qf[kd] = *reinterpret_cast<const bf16x8*>(Qb + (size_t)fr * DHc + kd * 32 + fo);

  f32x4 o[8] = {};
  float mrun[4], lrun[4];
#pragma unroll
  for (int r = 0; r < 4; ++r) { mrun[r] = -INFINITY; lrun[r] = 0.f; }

  const int nkb = (q0 + 16 + 31) >> 5;
  const float scale = 0.07216878364870323f;  // 1/sqrt(192)

  for (int kb = 0; kb < nkb; ++kb) {
    const int kbase = kb * 32;
    f32x4 s0 = {}, s1 = {};
#pragma unroll
    for (int kd = 0; kd < 6; ++kd) {
      bf16x8 kf = *reinterpret_cast<const bf16x8*>(Kb + (size_t)(kbase + fr) * DHc + kd * 32 + fo);
      s0 = __builtin_amdgcn_mfma_f32_16x16x32_bf16(qf[kd], kf, s0, 0, 0, 0);
    }
#pragma unroll
    for (int kd = 0; kd < 6; ++kd) {
      bf16x8 kf = *reinterpret_cast<const bf16x8*>(Kb + (size_t)(kbase + 16 + fr) * DHc + kd * 32 + fo);
      s1 = __builtin_amdgcn_mfma_f32_16x16x32_bf16(qf[kd], kf, s1, 0, 0, 0);
    }
    const int col0 = kbase + fr, col1 = kbase + 16 + fr;
    float pm[4], cfac[4], rsum[4];
#pragma unroll
    for (int r = 0; r < 4; ++r) {
      const int row = q0 + rg * 4 + r;
      float v0 = (col0 <= row) ? s0[r] * scale : -3.0e38f;
      float v1 = (col1 <= row) ? s1[r] * scale : -3.0e38f;
      s0[r] = v0; s1[r] = v1;
      pm[r] = fmaxf(v0, v1);
    }
#pragma unroll
    for (int msk = 1; msk < 16; msk <<= 1) {
#pragma unroll
      for (int r = 0; r < 4; ++r) pm[r] = fmaxf(pm[r], __shfl_xor(pm[r], msk, 64));
    }
#pragma unroll
    for (int r = 0; r < 4; ++r) {
      const float mnew = fmaxf(mrun[r], pm[r]);
      cfac[r] = __expf(mrun[r] - mnew);
      mrun[r] = mnew;
      const float p0 = __expf(s0[r] - mnew);
      const float p1 = __expf(s1[r] - mnew);
      s0[r] = p0; s1[r] = p1;
      rsum[r] = p0 + p1;
    }
#pragma unroll
    for (int msk = 1; msk < 16; msk <<= 1) {
#pragma unroll
      for (int r = 0; r < 4; ++r) rsum[r] += __shfl_xor(rsum[r], msk, 64);
    }
#pragma unroll
    for (int r = 0; r < 4; ++r) {
      lrun[r] = lrun[r] * cfac[r] + rsum[r];
#pragma unroll
      for (int dt = 0; dt < 8; ++dt) o[dt][r] *= cfac[r];
    }
    // P -> bf16 -> per-wave LDS tile, re-read in A-fragment layout
#pragma unroll
    for (int r = 0; r < 4; ++r) {
      P_lds[wave][rg * 4 + r][fr] = f2bf(s0[r]);
      P_lds[wave][rg * 4 + r][16 + fr] = f2bf(s1[r]);
    }
    bf16x8 pf = *reinterpret_cast<const bf16x8*>(&P_lds[wave][fr][fo]);
#pragma unroll
    for (int dt = 0; dt < 8; ++dt) {
      bf16x8 vf = *reinterpret_cast<const bf16x8*>(Vb + (size_t)(dt * 16 + fr) * Sc + kbase + fo);
      o[dt] = __builtin_amdgcn_mfma_f32_16x16x32_bf16(pf, vf, o[dt], 0, 0, 0);
    }
  }
#pragma unroll
  for (int r = 0; r < 4; ++r) {
    const float inv = 1.0f / lrun[r];
    const int row = q0 + rg * 4 + r;
    unsigned short* dst = attnOut + ((size_t)b * Sc + row) * (Hc * DVc) + h * DVc;
#pragma unroll
    for (int dt = 0; dt < 8; ++dt)
      dst[dt * 16 + fr] = f2bf(o[dt][r] * inv);
  }
}

// ---------------- host launch ----------------
extern "C" void kernel_launch(void* const* d_in, const int* in_sizes, int n_in,
                              void* d_out, int out_size, void* d_ws, size_t ws_size,
                              hipStream_t stream) {
  (void)in_sizes; (void)n_in; (void)out_size; (void)ws_size;
  const float* hidden = (const float*)d_in[0];
  const float* w_qa  = (const float*)d_in[2];
  const float* b_qa  = (const float*)d_in[3];
  const float* g_q   = (const float*)d_in[4];
  const float* w_qb  = (const float*)d_in[5];
  const float* b_qb  = (const float*)d_in[6];
  const float* w_kva = (const float*)d_in[7];
  const float* b_kva = (const float*)d_in[8];
  const float* g_kv  = (const float*)d_in[9];
  const float* w_kvb = (const float*)d_in[10];
  const float* b_kvb = (const float*)d_in[11];
  const float* w_o   = (const float*)d_in[12];
  const float* b_o   = (const float*)d_in[13];
  float* out = (float*)d_out;

  char* ws = (char*)d_ws;
  size_t off = 0;
  auto alloc = [&](size_t bytes) -> void* {
    void* p = ws + off;
    off += (bytes + 255) & ~(size_t)255;
    return p;
  };
  const int MS = Bc * Sc;  // 4096 rows

  unsigned short* Xbf  = (unsigned short*)alloc((size_t)MS * Dc * 2);
  unsigned short* Wqa  = (unsigned short*)alloc((size_t)Dc * RQc * 2);
  unsigned short* Wqb  = (unsigned short*)alloc((size_t)RQc * Hc * DHc * 2);
  unsigned short* Wkva = (unsigned short*)alloc((size_t)Dc * (RKVc + DRc) * 2);
  unsigned short* Wkvb = (unsigned short*)alloc((size_t)RKVc * HKVc * 256 * 2);
  unsigned short* Wo   = (unsigned short*)alloc((size_t)Hc * DVc * Dc * 2);
  float* cosT = (float*)alloc((size_t)Sc * DRc * 4);
  float* sinT = (float*)alloc((size_t)Sc * DRc * 4);
  float* qa   = (float*)alloc((size_t)MS * RQc * 4);
  unsigned short* qan  = (unsigned short*)alloc((size_t)MS * RQc * 2);
  unsigned short* qb   = (unsigned short*)alloc((size_t)MS * Hc * DHc * 2);
  float* kva  = (float*)alloc((size_t)MS * (RKVc + DRc) * 4);
  unsigned short* kvcn = (unsigned short*)alloc((size_t)MS * RKVc * 2);
  unsigned short* kvb  = (unsigned short*)alloc((size_t)MS * HKVc * 256 * 2);
  unsigned short* Qt   = (unsigned short*)alloc((size_t)Bc * Hc * Sc * DHc * 2);
  unsigned short* Kt   = (unsigned short*)alloc((size_t)Bc * HKVc * Sc * DHc * 2);
  unsigned short* Vt   = (unsigned short*)alloc((size_t)Bc * HKVc * DVc * Sc * 2);
  unsigned short* attnb= (unsigned short*)alloc((size_t)MS * Hc * DVc * 2);

  auto f2b = [&](const float* src, unsigned short* dst, int n) {
    f2b_kernel<<<dim3(512), dim3(256), 0, stream>>>(src, dst, n);
  };
  f2b(hidden, Xbf, MS * Dc);
  f2b(w_qa, Wqa, Dc * RQc);
  f2b(w_qb, Wqb, RQc * Hc * DHc);
  f2b(w_kva, Wkva, Dc * (RKVc + DRc));
  f2b(w_kvb, Wkvb, RKVc * HKVc * 256);
  f2b(w_o, Wo, Hc * DVc * Dc);
  rope_table_kernel<<<dim3(512), dim3(256), 0, stream>>>(cosT, sinT);

  // q_a = X @ w_qa + b_qa   (f32 out for rmsnorm)
  gemm_kernel<false, false><<<dim3(RQc / 128, MS / 128), 256, 0, stream>>>(Xbf, Wqa, b_qa, qa, MS, RQc, Dc);
  rmsnorm_kernel<1024><<<dim3(MS), 256, 0, stream>>>(qa, RQc, g_q, qan);
  // q_b = rmsnorm(q_a) @ w_qb + b_qb   (bf16 out)
  gemm_kernel<true, false><<<dim3(Hc * DHc / 128, MS / 128), 256, 0, stream>>>(qan, Wqb, b_qb, qb, MS, Hc * DHc, RQc);
  // kv_a = X @ w_kva + b_kva   (f32 out, N=576 guarded)
  gemm_kernel<false, true><<<dim3((RKVc + DRc + 127) / 128, MS / 128), 256, 0, stream>>>(Xbf, Wkva, b_kva, kva, MS, RKVc + DRc, Dc);
  rmsnorm_kernel<512><<<dim3(MS), 256, 0, stream>>>(kva, RKVc + DRc, g_kv, kvcn);
  // kv_b = rmsnorm(kv_c) @ w_kvb + b_kvb   (bf16 out)
  gemm_kernel<true, false><<<dim3(HKVc * 256 / 128, MS / 128), 256, 0, stream>>>(kvcn, Wkvb, b_kvb, kvb, MS, HKVc * 256, RKVc);

  prep_q_kernel<<<dim3(MS), 256, 0, stream>>>(qb, cosT, sinT, Qt);
  prep_k_kernel<<<dim3(MS), 256, 0, stream>>>(kvb, kva, cosT, sinT, Kt);
  vtrans_kernel<<<dim3(Bc * HKVc * (Sc / 32) * (DVc / 32)), 256, 0, stream>>>(kvb, Vt);

  attn_kernel<<<dim3(Bc * Hc, Sc / 64), 256, 0, stream>>>(Qt, Kt, Vt, attnb);

  // out = attn @ w_o + b_o  (f32 straight to d_out)
  gemm_kernel<false, false><<<dim3(Dc / 128, MS / 128), 256, 0, stream>>>(attnb, Wo, b_o, out, MS, Dc, Hc * DVc);
}

// Round 2
// 528.922 us; speedup vs baseline: 1.3925x; 1.3925x over previous
//
#include <hip/hip_runtime.h>
#include <hip/hip_bf16.h>
#include <stdint.h>

#define DEV static __device__ __forceinline__

typedef __attribute__((ext_vector_type(8))) short bf16x8;
typedef __attribute__((ext_vector_type(4))) short bf16x4;
typedef __attribute__((ext_vector_type(4))) float f32x4;
typedef __attribute__((ext_vector_type(16))) float f32x16;

constexpr int Bc = 2, Sc = 2048, Dc = 2048;
constexpr int Hc = 16, HKVc = 4;
constexpr int RQc = 1024, RKVc = 512;
constexpr int DHc = 192, DRc = 64, DVc = 128;

DEV unsigned short f2bf(float f) {
  union { float f; uint32_t u; } v; v.f = f;
  uint32_t r = v.u + 0x7FFFu + ((v.u >> 16) & 1u);
  return (unsigned short)(r >> 16);
}
DEV float bf2f(unsigned short u) {
  union { uint32_t u; float f; } v; v.u = ((uint32_t)u) << 16;
  return v.f;
}

// ---------------- f32 -> bf16 conversion (vectorized) ----------------
__global__ void f2b_kernel(const float* __restrict__ in, unsigned short* __restrict__ out, int n) {
  int stride = gridDim.x * blockDim.x;
  for (int i = blockIdx.x * blockDim.x + threadIdx.x; i * 4 < n; i += stride) {
    float4 v = reinterpret_cast<const float4*>(in)[i];
    union { unsigned short u[4]; uint64_t q; } pk;
    pk.u[0] = f2bf(v.x); pk.u[1] = f2bf(v.y); pk.u[2] = f2bf(v.z); pk.u[3] = f2bf(v.w);
    reinterpret_cast<uint64_t*>(out)[i] = pk.q;
  }
}

// ---------------- RoPE cos/sin table ----------------
__global__ void rope_table_kernel(float* __restrict__ cosT, float* __restrict__ sinT) {
  int idx = blockIdx.x * blockDim.x + threadIdx.x;
  if (idx >= Sc * DRc) return;
  int t = idx >> 6;
  int j = idx & 63;
  float inv = exp2f(-13.287712379549449f * (float)(j & 31) * (1.0f / 32.0f));
  float f = (float)t * inv;
  cosT[idx] = cosf(f);
  sinT[idx] = sinf(f);
}

// ---------------- RMSNorm (block per row), f32 in -> bf16 out ----------------
template<int R>
__global__ void rmsnorm_kernel(const float* __restrict__ in, int istride,
                               const float* __restrict__ g, unsigned short* __restrict__ out) {
  int row = blockIdx.x;
  const float* x = in + (size_t)row * istride;
  float ss = 0.f;
  for (int j = threadIdx.x; j < R; j += 256) { float v = x[j]; ss += v * v; }
  for (int off = 32; off; off >>= 1) ss += __shfl_down(ss, off, 64);
  __shared__ float wsum[4];
  if ((threadIdx.x & 63) == 0) wsum[threadIdx.x >> 6] = ss;
  __syncthreads();
  float tot = wsum[0] + wsum[1] + wsum[2] + wsum[3];
  float rs = rsqrtf(tot * (1.0f / R) + 1e-20f);
  for (int j = threadIdx.x; j < R; j += 256)
    out[(size_t)row * R + j] = f2bf(x[j] * rs * g[j]);
}

// ---------------- GEMM: C[M,N] = A[M,K](bf16) @ B[K,N](bf16) + bias ----------------
template<bool OUT_BF16, bool NG>
__global__ __launch_bounds__(256)
void gemm_kernel(const unsigned short* __restrict__ A, const unsigned short* __restrict__ Bw,
                 const float* __restrict__ bias, void* __restrict__ Cout,
                 int M, int N, int K) {
  constexpr int BK = 64;
  __shared__ __align__(16) unsigned short As[128][72];
  __shared__ __align__(16) unsigned short Bt[128][72];
  const int t = threadIdx.x;
  const int lane = t & 63;
  const int wave = t >> 6;
  const int wm = wave >> 1, wn = wave & 1;
  const int m0 = blockIdx.y * 128, n0 = blockIdx.x * 128;
  const int fr = lane & 15, fo = (lane >> 4) * 8, rg = lane >> 4;

  const int a_row = t >> 1, a_cg = (t & 1) * 32;
  const int b_n = (t & 15) * 8;
  const int b_kq = (t >> 4);
  const bool bok = !NG || (n0 + b_n + 8 <= N);

  f32x4 acc[4][4] = {};

  bf16x8 av[4], bv[4];
  auto load_tile = [&](int k0) {
    const unsigned short* ap = A + (size_t)(m0 + a_row) * K + k0 + a_cg;
    av[0] = *reinterpret_cast<const bf16x8*>(ap);
    av[1] = *reinterpret_cast<const bf16x8*>(ap + 8);
    av[2] = *reinterpret_cast<const bf16x8*>(ap + 16);
    av[3] = *reinterpret_cast<const bf16x8*>(ap + 24);
    if (bok) {
      const unsigned short* bp = Bw + (size_t)(k0 + b_kq * 4) * N + n0 + b_n;
      bv[0] = *reinterpret_cast<const bf16x8*>(bp);
      bv[1] = *reinterpret_cast<const bf16x8*>(bp + N);
      bv[2] = *reinterpret_cast<const bf16x8*>(bp + 2 * N);
      bv[3] = *reinterpret_cast<const bf16x8*>(bp + 3 * N);
    } else {
      bf16x8 z = {0, 0, 0, 0, 0, 0, 0, 0};
      bv[0] = z; bv[1] = z; bv[2] = z; bv[3] = z;
    }
  };

  load_tile(0);
  for (int k0 = 0; k0 < K; k0 += BK) {
    __syncthreads();
    *reinterpret_cast<bf16x8*>(&As[a_row][a_cg]) = av[0];
    *reinterpret_cast<bf16x8*>(&As[a_row][a_cg + 8]) = av[1];
    *reinterpret_cast<bf16x8*>(&As[a_row][a_cg + 16]) = av[2];
    *reinterpret_cast<bf16x8*>(&As[a_row][a_cg + 24]) = av[3];
#pragma unroll
    for (int j = 0; j < 8; ++j) {
      bf16x4 w = { bv[0][j], bv[1][j], bv[2][j], bv[3][j] };
      *reinterpret_cast<bf16x4*>(&Bt[b_n + j][b_kq * 4]) = w;
    }
    __syncthreads();
    if (k0 + BK < K) load_tile(k0 + BK);
#pragma unroll
    for (int kk = 0; kk < BK; kk += 32) {
      bf16x8 af[4], bfr[4];
#pragma unroll
      for (int m = 0; m < 4; ++m)
        af[m] = *reinterpret_cast<const bf16x8*>(&As[wm * 64 + m * 16 + fr][kk + fo]);
#pragma unroll
      for (int n = 0; n < 4; ++n)
        bfr[n] = *reinterpret_cast<const bf16x8*>(&Bt[wn * 64 + n * 16 + fr][kk + fo]);
#pragma unroll
      for (int m = 0; m < 4; ++m)
#pragma unroll
        for (int n = 0; n < 4; ++n)
          acc[m][n] = __builtin_amdgcn_mfma_f32_16x16x32_bf16(af[m], bfr[n], acc[m][n], 0, 0, 0);
    }
  }
#pragma unroll
  for (int m = 0; m < 4; ++m) {
    const int row = m0 + wm * 64 + m * 16 + rg * 4;
#pragma unroll
    for (int n = 0; n < 4; ++n) {
      const int col = n0 + wn * 64 + n * 16 + fr;
      if (NG && col >= N) continue;
      const float bb = bias[col];
#pragma unroll
      for (int r = 0; r < 4; ++r) {
        float v = acc[m][n][r] + bb;
        if (OUT_BF16)
          reinterpret_cast<unsigned short*>(Cout)[(size_t)(row + r) * N + col] = f2bf(v);
        else
          reinterpret_cast<float*>(Cout)[(size_t)(row + r) * N + col] = v;
      }
    }
  }
}

// ---------------- prep Q ----------------
__global__ void prep_q_kernel(const unsigned short* __restrict__ qb,
                              const float* __restrict__ cosT, const float* __restrict__ sinT,
                              unsigned short* __restrict__ Q) {
  int bs = blockIdx.x;
  int s = bs & (Sc - 1);
  int b = bs >> 11;
  int d = threadIdx.x;
  if (d >= 192) return;
  for (int h = 0; h < Hc; ++h) {
    const unsigned short* src = qb + (size_t)bs * (Hc * DHc) + h * DHc;
    unsigned short o;
    if (d < 128) {
      o = src[d];
    } else {
      int j = d - 128;
      float x = bf2f(src[128 + j]);
      float other = bf2f(src[128 + (j < 32 ? j + 32 : j - 32)]);
      float c = cosT[s * 64 + j], sn = sinT[s * 64 + j];
      float v = (j < 32) ? (x * c - other * sn) : (x * c + other * sn);
      o = f2bf(v);
    }
    Q[(((size_t)(b * Hc + h)) * Sc + s) * DHc + d] = o;
  }
}

// ---------------- prep K ----------------
__global__ void prep_k_kernel(const unsigned short* __restrict__ kvb,
                              const float* __restrict__ kva,
                              const float* __restrict__ cosT, const float* __restrict__ sinT,
                              unsigned short* __restrict__ K) {
  int bs = blockIdx.x;
  int s = bs & (Sc - 1);
  int b = bs >> 11;
  int d = threadIdx.x;
  if (d >= 192) return;
  unsigned short ropeval = 0;
  if (d >= 128) {
    int j = d - 128;
    float x = kva[(size_t)bs * 576 + 512 + j];
    float other = kva[(size_t)bs * 576 + 512 + (j < 32 ? j + 32 : j - 32)];
    float c = cosT[s * 64 + j], sn = sinT[s * 64 + j];
    float v = (j < 32) ? (x * c - other * sn) : (x * c + other * sn);
    ropeval = f2bf(v);
  }
  for (int kvh = 0; kvh < HKVc; ++kvh) {
    unsigned short o;
    if (d < 128) o = kvb[(size_t)bs * 1024 + kvh * 256 + d];
    else o = ropeval;
    K[(((size_t)(b * HKVc + kvh)) * Sc + s) * DHc + d] = o;
  }
}

// ---------------- V transpose: kv_b[...,128:256] -> Vt[B,HKV,128,S] ----------------
__global__ void vtrans_kernel(const unsigned short* __restrict__ kvb, unsigned short* __restrict__ Vt) {
  int idx = blockIdx.x;
  int dt = idx & 3;  idx >>= 2;
  int st = idx & 63; idx >>= 6;
  int kvh = idx & 3; idx >>= 2;
  int b = idx;
  __shared__ unsigned short tile[32][33];
  int t = threadIdx.x;
  int c = t & 31, r0 = t >> 5;
#pragma unroll
  for (int i = 0; i < 4; ++i) {
    int r = r0 + i * 8;
    int s = st * 32 + r;
    tile[r][c] = kvb[((size_t)(b * Sc + s)) * 1024 + kvh * 256 + 128 + dt * 32 + c];
  }
  __syncthreads();
#pragma unroll
  for (int i = 0; i < 4; ++i) {
    int r = r0 + i * 8;
    Vt[((size_t)((b * HKVc + kvh) * DVc + dt * 32 + r)) * Sc + st * 32 + c] = tile[c][r];
  }
}

// ---------------- flash attention, swapped-operand 32x32 ----------------
// 256 blocks x 4 waves = 1024 waves; wave gw processes q-tiles (pr, 63-pr) of
// head (gw&31) -> exactly 65 kv-block iterations per wave (perfect balance).
// QK^T computed swapped: mfma(K,Q) => lane holds 16 key-scores for ONE q row
// (q = lane&31) -> softmax is in-register (15 fmax + 1 shfl_xor(32)).
// O accumulated transposed: mfma(Vt,P^T) => col = q = lane&31, so rescale
// factors stay lane-local. K prefetched one block ahead; V issued before QK.
__global__ __launch_bounds__(256, 1)
void attn_kernel(const unsigned short* __restrict__ Q, const unsigned short* __restrict__ Kt,
                 const unsigned short* __restrict__ Vt, unsigned short* __restrict__ attnOut) {
  const int gw = blockIdx.x * 4 + (threadIdx.x >> 6);
  const int lane = threadIdx.x & 63;
  const int bh = gw & 31;
  const int pr = gw >> 5;
  const int b = bh >> 4, h = bh & 15;
  const int kvh = h >> 2;
  const int l31 = lane & 31;
  const int hi = lane >> 5;
  const float scale = 0.07216878364870323f;  // 1/sqrt(192)

  const unsigned short* Qh = Q + (size_t)(b * Hc + h) * Sc * DHc;
  const unsigned short* Kh = Kt + (size_t)(b * HKVc + kvh) * Sc * DHc;
  const unsigned short* Vh = Vt + (size_t)(b * HKVc + kvh) * DVc * Sc;

  for (int half = 0; half < 2; ++half) {
    const int tile = half ? (63 - pr) : pr;
    const int q0 = tile * 32;
    const int q = q0 + l31;

    bf16x8 qf[12];
#pragma unroll
    for (int f = 0; f < 12; ++f)
      qf[f] = *reinterpret_cast<const bf16x8*>(Qh + (size_t)q * DHc + f * 16 + hi * 8);

    f32x16 ot[4] = {};
    float m = -INFINITY, lsum = 0.f;
    const int nkb = tile + 1;

    bf16x8 kf[12];
#pragma unroll
    for (int f = 0; f < 12; ++f)
      kf[f] = *reinterpret_cast<const bf16x8*>(Kh + (size_t)l31 * DHc + f * 16 + hi * 8);

    for (int kb = 0; kb < nkb; ++kb) {
      const int kbase = kb * 32;
      // V fragments for this block (consumed after softmax -> latency hidden)
      bf16x8 vf[8];
#pragma unroll
      for (int dt = 0; dt < 4; ++dt)
#pragma unroll
        for (int k2 = 0; k2 < 2; ++k2)
          vf[dt * 2 + k2] = *reinterpret_cast<const bf16x8*>(
              Vh + (size_t)(dt * 32 + l31) * Sc + kbase + k2 * 16 + hi * 8);

      f32x16 s = {};
#pragma unroll
      for (int f = 0; f < 12; ++f)
        s = __builtin_amdgcn_mfma_f32_32x32x16_bf16(kf[f], qf[f], s, 0, 0, 0);

      // prefetch next K block (consumed next iteration -> latency hidden)
      const int knext = (kbase + 32 < Sc) ? kbase + 32 : kbase;
#pragma unroll
      for (int f = 0; f < 12; ++f)
        kf[f] = *reinterpret_cast<const bf16x8*>(Kh + (size_t)(knext + l31) * DHc + f * 16 + hi * 8);

      // mask + scale; key index for s[r] is kbase + (r&3)+8*(r>>2)+4*hi
      float v[16];
#pragma unroll
      for (int r = 0; r < 16; ++r) {
        const int key = kbase + (r & 3) + 8 * (r >> 2) + 4 * hi;
        v[r] = (key <= q) ? s[r] * scale : -3.0e38f;
      }
      float pmax = v[0];
#pragma unroll
      for (int r = 1; r < 16; ++r) pmax = fmaxf(pmax, v[r]);
      pmax = fmaxf(pmax, __shfl_xor(pmax, 32, 64));

      float cf = 1.f;
      if (!__all(pmax - m <= 8.0f)) {   // defer-max: skip O rescale when safe
        const float mnew = fmaxf(m, pmax);
        cf = __expf(m - mnew);
        m = mnew;
#pragma unroll
        for (int dt = 0; dt < 4; ++dt)
#pragma unroll
          for (int r = 0; r < 16; ++r) ot[dt][r] *= cf;
      }

      float p[16];
      float rs = 0.f;
#pragma unroll
      for (int r = 0; r < 16; ++r) { p[r] = __expf(v[r] - m); rs += p[r]; }
      rs += __shfl_xor(rs, 32, 64);
      lsum = lsum * cf + rs;

      // pack P to bf16 pairs; exchange halves so each lane holds the B-frag
      // (P^T) key-slices it needs: k = kb16*16 + hi*8 + j
      uint32_t c[8], x[8];
#pragma unroll
      for (int i = 0; i < 8; ++i) {
        c[i] = (uint32_t)f2bf(p[2 * i]) | ((uint32_t)f2bf(p[2 * i + 1]) << 16);
        x[i] = (uint32_t)__shfl_xor((int)c[i], 32, 64);
      }
      union { uint32_t w[4]; bf16x8 v8; } pa0, pa1;
      pa0.w[0] = hi ? x[2] : c[0];
      pa0.w[1] = hi ? x[3] : c[1];
      pa0.w[2] = hi ? c[2] : x[0];
      pa0.w[3] = hi ? c[3] : x[1];
      pa1.w[0] = hi ? x[6] : c[4];
      pa1.w[1] = hi ? x[7] : c[5];
      pa1.w[2] = hi ? c[6] : x[4];
      pa1.w[3] = hi ? c[7] : x[5];

#pragma unroll
      for (int dt = 0; dt < 4; ++dt) {
        ot[dt] = __builtin_amdgcn_mfma_f32_32x32x16_bf16(vf[dt * 2], pa0.v8, ot[dt], 0, 0, 0);
        ot[dt] = __builtin_amdgcn_mfma_f32_32x32x16_bf16(vf[dt * 2 + 1], pa1.v8, ot[dt], 0, 0, 0);
      }
    }

    const float inv = 1.0f / lsum;
    unsigned short* dst = attnOut + ((size_t)(b * Sc + q)) * (Hc * DVc) + h * DVc;
#pragma unroll
    for (int dt = 0; dt < 4; ++dt)
#pragma unroll
      for (int rq = 0; rq < 4; ++rq) {
        uint32_t lo = (uint32_t)f2bf(ot[dt][rq * 4 + 0] * inv) |
                      ((uint32_t)f2bf(ot[dt][rq * 4 + 1] * inv) << 16);
        uint32_t hi2 = (uint32_t)f2bf(ot[dt][rq * 4 + 2] * inv) |
                       ((uint32_t)f2bf(ot[dt][rq * 4 + 3] * inv) << 16);
        uint2 pk; pk.x = lo; pk.y = hi2;
        *reinterpret_cast<uint2*>(dst + dt * 32 + 8 * rq + 4 * hi) = pk;
      }
  }
}

// ---------------- host launch ----------------
extern "C" void kernel_launch(void* const* d_in, const int* in_sizes, int n_in,
                              void* d_out, int out_size, void* d_ws, size_t ws_size,
                              hipStream_t stream) {
  (void)in_sizes; (void)n_in; (void)out_size; (void)ws_size;
  const float* hidden = (const float*)d_in[0];
  const float* w_qa  = (const float*)d_in[2];
  const float* b_qa  = (const float*)d_in[3];
  const float* g_q   = (const float*)d_in[4];
  const float* w_qb  = (const float*)d_in[5];
  const float* b_qb  = (const float*)d_in[6];
  const float* w_kva = (const float*)d_in[7];
  const float* b_kva = (const float*)d_in[8];
  const float* g_kv  = (const float*)d_in[9];
  const float* w_kvb = (const float*)d_in[10];
  const float* b_kvb = (const float*)d_in[11];
  const float* w_o   = (const float*)d_in[12];
  const float* b_o   = (const float*)d_in[13];
  float* out = (float*)d_out;

  char* ws = (char*)d_ws;
  size_t off = 0;
  auto alloc = [&](size_t bytes) -> void* {
    void* p = ws + off;
    off += (bytes + 255) & ~(size_t)255;
    return p;
  };
  const int MS = Bc * Sc;  // 4096 rows

  unsigned short* Xbf  = (unsigned short*)alloc((size_t)MS * Dc * 2);
  unsigned short* Wqa  = (unsigned short*)alloc((size_t)Dc * RQc * 2);
  unsigned short* Wqb  = (unsigned short*)alloc((size_t)RQc * Hc * DHc * 2);
  unsigned short* Wkva = (unsigned short*)alloc((size_t)Dc * (RKVc + DRc) * 2);
  unsigned short* Wkvb = (unsigned short*)alloc((size_t)RKVc * HKVc * 256 * 2);
  unsigned short* Wo   = (unsigned short*)alloc((size_t)Hc * DVc * Dc * 2);
  float* cosT = (float*)alloc((size_t)Sc * DRc * 4);
  float* sinT = (float*)alloc((size_t)Sc * DRc * 4);
  float* qa   = (float*)alloc((size_t)MS * RQc * 4);
  unsigned short* qan  = (unsigned short*)alloc((size_t)MS * RQc * 2);
  unsigned short* qb   = (unsigned short*)alloc((size_t)MS * Hc * DHc * 2);
  float* kva  = (float*)alloc((size_t)MS * (RKVc + DRc) * 4);
  unsigned short* kvcn = (unsigned short*)alloc((size_t)MS * RKVc * 2);
  unsigned short* kvb  = (unsigned short*)alloc((size_t)MS * HKVc * 256 * 2);
  unsigned short* Qt   = (unsigned short*)alloc((size_t)Bc * Hc * Sc * DHc * 2);
  unsigned short* Kt   = (unsigned short*)alloc((size_t)Bc * HKVc * Sc * DHc * 2);
  unsigned short* Vt   = (unsigned short*)alloc((size_t)Bc * HKVc * DVc * Sc * 2);
  unsigned short* attnb= (unsigned short*)alloc((size_t)MS * Hc * DVc * 2);

  auto f2b = [&](const float* src, unsigned short* dst, int n) {
    f2b_kernel<<<dim3(512), dim3(256), 0, stream>>>(src, dst, n);
  };
  f2b(hidden, Xbf, MS * Dc);
  f2b(w_qa, Wqa, Dc * RQc);
  f2b(w_qb, Wqb, RQc * Hc * DHc);
  f2b(w_kva, Wkva, Dc * (RKVc + DRc));
  f2b(w_kvb, Wkvb, RKVc * HKVc * 256);
  f2b(w_o, Wo, Hc * DVc * Dc);
  rope_table_kernel<<<dim3(512), dim3(256), 0, stream>>>(cosT, sinT);

  gemm_kernel<false, false><<<dim3(RQc / 128, MS / 128), 256, 0, stream>>>(Xbf, Wqa, b_qa, qa, MS, RQc, Dc);
  rmsnorm_kernel<1024><<<dim3(MS), 256, 0, stream>>>(qa, RQc, g_q, qan);
  gemm_kernel<true, false><<<dim3(Hc * DHc / 128, MS / 128), 256, 0, stream>>>(qan, Wqb, b_qb, qb, MS, Hc * DHc, RQc);
  gemm_kernel<false, true><<<dim3((RKVc + DRc + 127) / 128, MS / 128), 256, 0, stream>>>(Xbf, Wkva, b_kva, kva, MS, RKVc + DRc, Dc);
  rmsnorm_kernel<512><<<dim3(MS), 256, 0, stream>>>(kva, RKVc + DRc, g_kv, kvcn);
  gemm_kernel<true, false><<<dim3(HKVc * 256 / 128, MS / 128), 256, 0, stream>>>(kvcn, Wkvb, b_kvb, kvb, MS, HKVc * 256, RKVc);

  prep_q_kernel<<<dim3(MS), 256, 0, stream>>>(qb, cosT, sinT, Qt);
  prep_k_kernel<<<dim3(MS), 256, 0, stream>>>(kvb, kva, cosT, sinT, Kt);
  vtrans_kernel<<<dim3(Bc * HKVc * (Sc / 32) * (DVc / 32)), 256, 0, stream>>>(kvb, Vt);

  attn_kernel<<<dim3(256), dim3(256), 0, stream>>>(Qt, Kt, Vt, attnb);

  gemm_kernel<false, false><<<dim3(Dc / 128, MS / 128), 256, 0, stream>>>(attnb, Wo, b_o, out, MS, Dc, Hc * DVc);
}

// Round 3
// 449.330 us; speedup vs baseline: 1.6391x; 1.1771x over previous
//
#include <hip/hip_runtime.h>
#include <hip/hip_bf16.h>
#include <stdint.h>

#define DEV static __device__ __forceinline__

typedef __attribute__((ext_vector_type(8))) short bf16x8;
typedef __attribute__((ext_vector_type(4))) float f32x4;
typedef __attribute__((ext_vector_type(16))) float f32x16;

constexpr int Bc = 2, Sc = 2048, Dc = 2048;
constexpr int Hc = 16, HKVc = 4;
constexpr int RQc = 1024, RKVc = 512;
constexpr int DHc = 192, DRc = 64, DVc = 128;

DEV unsigned short f2bf(float f) {
  union { float f; uint32_t u; } v; v.f = f;
  uint32_t r = v.u + 0x7FFFu + ((v.u >> 16) & 1u);
  return (unsigned short)(r >> 16);
}
DEV float bf2f(unsigned short u) {
  union { uint32_t u; float f; } v; v.u = ((uint32_t)u) << 16;
  return v.f;
}

DEV void gload_lds16(const unsigned short* g, unsigned short* l) {
  __builtin_amdgcn_global_load_lds(
      (const __attribute__((address_space(1))) unsigned int*)g,
      (__attribute__((address_space(3))) unsigned int*)l, 16, 0, 0);
}

// ---------------- f32 -> bf16 conversion (vectorized) ----------------
__global__ void f2b_kernel(const float* __restrict__ in, unsigned short* __restrict__ out, int n) {
  int stride = gridDim.x * blockDim.x;
  for (int i = blockIdx.x * blockDim.x + threadIdx.x; i * 4 < n; i += stride) {
    float4 v = reinterpret_cast<const float4*>(in)[i];
    union { unsigned short u[4]; uint64_t q; } pk;
    pk.u[0] = f2bf(v.x); pk.u[1] = f2bf(v.y); pk.u[2] = f2bf(v.z); pk.u[3] = f2bf(v.w);
    reinterpret_cast<uint64_t*>(out)[i] = pk.q;
  }
}

// ---------------- weight transpose: in[R][C] f32 -> out[C][R] bf16 ----------------
__global__ void wtrans_kernel(const float* __restrict__ in, unsigned short* __restrict__ out,
                              int R, int C) {
  __shared__ float tile[32][33];
  const int c0 = blockIdx.x * 32, r0 = blockIdx.y * 32;
  const int tx = threadIdx.x & 31, ty = threadIdx.x >> 5;  // ty 0..7
#pragma unroll
  for (int i = 0; i < 32; i += 8)
    tile[ty + i][tx] = in[(size_t)(r0 + ty + i) * C + c0 + tx];
  __syncthreads();
#pragma unroll
  for (int i = 0; i < 32; i += 8)
    out[(size_t)(c0 + ty + i) * R + r0 + tx] = f2bf(tile[tx][ty + i]);
}

// ---------------- RoPE cos/sin table ----------------
__global__ void rope_table_kernel(float* __restrict__ cosT, float* __restrict__ sinT) {
  int idx = blockIdx.x * blockDim.x + threadIdx.x;
  if (idx >= Sc * DRc) return;
  int t = idx >> 6;
  int j = idx & 63;
  float inv = exp2f(-13.287712379549449f * (float)(j & 31) * (1.0f / 32.0f));
  float f = (float)t * inv;
  cosT[idx] = cosf(f);
  sinT[idx] = sinf(f);
}

// ---------------- RMSNorm (block per row), f32 in -> bf16 out ----------------
template<int R>
__global__ void rmsnorm_kernel(const float* __restrict__ in, int istride,
                               const float* __restrict__ g, unsigned short* __restrict__ out) {
  int row = blockIdx.x;
  const float* x = in + (size_t)row * istride;
  float ss = 0.f;
  for (int j = threadIdx.x; j < R; j += 256) { float v = x[j]; ss += v * v; }
  for (int off = 32; off; off >>= 1) ss += __shfl_down(ss, off, 64);
  __shared__ float wsum[4];
  if ((threadIdx.x & 63) == 0) wsum[threadIdx.x >> 6] = ss;
  __syncthreads();
  float tot = wsum[0] + wsum[1] + wsum[2] + wsum[3];
  float rs = rsqrtf(tot * (1.0f / R) + 1e-20f);
  for (int j = threadIdx.x; j < R; j += 256)
    out[(size_t)row * R + j] = f2bf(x[j] * rs * g[j]);
}

// ---------------- GEMM (m97 structure): C[M,N] = A[M,K] @ Bt[N,K]^T + bias ----------------
// 128x128 tile, BK=64, 4 waves (2x2), global_load_lds width=16 into linear LDS,
// ds_read_b128 fragments, 2-barrier K-loop. Both operands k-contiguous.
template<bool OUT_BF16, bool NG>
__global__ __launch_bounds__(256)
void gemm_tn_kernel(const unsigned short* __restrict__ A, const unsigned short* __restrict__ Bt,
                    const float* __restrict__ bias, void* __restrict__ Cout,
                    int M, int N, int K) {
  __shared__ __align__(16) unsigned short As[128 * 64];
  __shared__ __align__(16) unsigned short Bs[128 * 64];
  const int t = threadIdx.x, lane = t & 63, wave = t >> 6;
  const int wm = wave >> 1, wn = wave & 1;
  const int m0 = blockIdx.y * 128, n0 = blockIdx.x * 128;
  const int fr = lane & 15, fo = (lane >> 4) * 8, rg = lane >> 4;
  const int srow = lane >> 3;        // 0..7 (row within 8-row group)
  const int scol = (lane & 7) * 8;   // k element offset

  const unsigned short* Ap[4];
  const unsigned short* Bp[4];
#pragma unroll
  for (int i = 0; i < 4; ++i) {
    const int ar = m0 + wave * 32 + i * 8 + srow;
    Ap[i] = A + (size_t)ar * K + scol;
    int br = n0 + wave * 32 + i * 8 + srow;
    if (NG) br = br < N ? br : N - 1;
    Bp[i] = Bt + (size_t)br * K + scol;
  }

  f32x4 acc[4][4] = {};

  for (int k0 = 0; k0 < K; k0 += 64) {
#pragma unroll
    for (int i = 0; i < 4; ++i) {
      gload_lds16(Ap[i] + k0, &As[(wave * 32 + i * 8) * 64]);
      gload_lds16(Bp[i] + k0, &Bs[(wave * 32 + i * 8) * 64]);
    }
    asm volatile("s_waitcnt vmcnt(0)" ::: "memory");
    __syncthreads();
#pragma unroll
    for (int kk = 0; kk < 64; kk += 32) {
      bf16x8 af[4], bf[4];
#pragma unroll
      for (int m = 0; m < 4; ++m)
        af[m] = *reinterpret_cast<const bf16x8*>(&As[(wm * 64 + m * 16 + fr) * 64 + kk + fo]);
#pragma unroll
      for (int n = 0; n < 4; ++n)
        bf[n] = *reinterpret_cast<const bf16x8*>(&Bs[(wn * 64 + n * 16 + fr) * 64 + kk + fo]);
#pragma unroll
      for (int m = 0; m < 4; ++m)
#pragma unroll
        for (int n = 0; n < 4; ++n)
          acc[m][n] = __builtin_amdgcn_mfma_f32_16x16x32_bf16(af[m], bf[n], acc[m][n], 0, 0, 0);
    }
    __syncthreads();
  }

#pragma unroll
  for (int m = 0; m < 4; ++m) {
    const int row = m0 + wm * 64 + m * 16 + rg * 4;
#pragma unroll
    for (int n = 0; n < 4; ++n) {
      const int col = n0 + wn * 64 + n * 16 + fr;
      if (NG && col >= N) continue;
      const float bb = bias[col];
#pragma unroll
      for (int r = 0; r < 4; ++r) {
        float v = acc[m][n][r] + bb;
        if (OUT_BF16)
          reinterpret_cast<unsigned short*>(Cout)[(size_t)(row + r) * N + col] = f2bf(v);
        else
          reinterpret_cast<float*>(Cout)[(size_t)(row + r) * N + col] = v;
      }
    }
  }
}

// ---------------- prep Q: rope + pre-scale by (1/sqrt(192))*log2(e) ----------------
__global__ void prep_q_kernel(const unsigned short* __restrict__ qb,
                              const float* __restrict__ cosT, const float* __restrict__ sinT,
                              unsigned short* __restrict__ Q) {
  const float QS = 0.07216878364870323f * 1.4426950408889634f;
  int bs = blockIdx.x;
  int s = bs & (Sc - 1);
  int b = bs >> 11;
  int d = threadIdx.x;
  if (d >= 192) return;
  for (int h = 0; h < Hc; ++h) {
    const unsigned short* src = qb + (size_t)bs * (Hc * DHc) + h * DHc;
    float v;
    if (d < 128) {
      v = bf2f(src[d]);
    } else {
      int j = d - 128;
      float x = bf2f(src[128 + j]);
      float other = bf2f(src[128 + (j < 32 ? j + 32 : j - 32)]);
      float c = cosT[s * 64 + j], sn = sinT[s * 64 + j];
      v = (j < 32) ? (x * c - other * sn) : (x * c + other * sn);
    }
    Q[(((size_t)(b * Hc + h)) * Sc + s) * DHc + d] = f2bf(v * QS);
  }
}

// ---------------- prep K ----------------
__global__ void prep_k_kernel(const unsigned short* __restrict__ kvb,
                              const float* __restrict__ kva,
                              const float* __restrict__ cosT, const float* __restrict__ sinT,
                              unsigned short* __restrict__ K) {
  int bs = blockIdx.x;
  int s = bs & (Sc - 1);
  int b = bs >> 11;
  int d = threadIdx.x;
  if (d >= 192) return;
  unsigned short ropeval = 0;
  if (d >= 128) {
    int j = d - 128;
    float x = kva[(size_t)bs * 576 + 512 + j];
    float other = kva[(size_t)bs * 576 + 512 + (j < 32 ? j + 32 : j - 32)];
    float c = cosT[s * 64 + j], sn = sinT[s * 64 + j];
    float v = (j < 32) ? (x * c - other * sn) : (x * c + other * sn);
    ropeval = f2bf(v);
  }
  for (int kvh = 0; kvh < HKVc; ++kvh) {
    unsigned short o;
    if (d < 128) o = kvb[(size_t)bs * 1024 + kvh * 256 + d];
    else o = ropeval;
    K[(((size_t)(b * HKVc + kvh)) * Sc + s) * DHc + d] = o;
  }
}

// ---------------- V transpose: kv_b[...,128:256] -> Vt[B,HKV,128,S] ----------------
__global__ void vtrans_kernel(const unsigned short* __restrict__ kvb, unsigned short* __restrict__ Vt) {
  int idx = blockIdx.x;
  int dt = idx & 3;  idx >>= 2;
  int st = idx & 63; idx >>= 6;
  int kvh = idx & 3; idx >>= 2;
  int b = idx;
  __shared__ unsigned short tile[32][33];
  int t = threadIdx.x;
  int c = t & 31, r0 = t >> 5;
#pragma unroll
  for (int i = 0; i < 4; ++i) {
    int r = r0 + i * 8;
    int s = st * 32 + r;
    tile[r][c] = kvb[((size_t)(b * Sc + s)) * 1024 + kvh * 256 + 128 + dt * 32 + c];
  }
  __syncthreads();
#pragma unroll
  for (int i = 0; i < 4; ++i) {
    int r = r0 + i * 8;
    Vt[((size_t)((b * HKVc + kvh) * DVc + dt * 32 + r)) * Sc + st * 32 + c] = tile[c][r];
  }
}

// ---------------- flash attention, swapped-operand 32x32, 1 wave/block ----------------
// 2048 one-wave blocks; block bid -> head (bid&31), tile via complementary-pair
// mapping so bid and bid+1024 sum to 65 kv-blocks (uniform SIMD load at 2 waves/SIMD).
// Q pre-scaled by (1/sqrt(192))*log2(e) -> scores in log2 domain, exp2f softmax.
// Only the diagonal kv-block is masked.
__global__ __launch_bounds__(64, 1)
void attn_kernel(const unsigned short* __restrict__ Q, const unsigned short* __restrict__ Kt,
                 const unsigned short* __restrict__ Vt, unsigned short* __restrict__ attnOut) {
  const int bid = blockIdx.x;
  const int bh = bid & 31;
  const int idx = bid >> 5;
  const int tl = (idx < 32) ? (63 - idx) : (idx - 32);
  const int lane = threadIdx.x;
  const int b = bh >> 4, h = bh & 15, kvh = h >> 2;
  const int l31 = lane & 31, hi = lane >> 5;

  const unsigned short* Qh = Q + (size_t)(b * Hc + h) * Sc * DHc;
  const unsigned short* Kh = Kt + (size_t)(b * HKVc + kvh) * Sc * DHc;
  const unsigned short* Vh = Vt + (size_t)(b * HKVc + kvh) * DVc * Sc;

  const int q0 = tl * 32;
  const int q = q0 + l31;

  bf16x8 qf[12];
#pragma unroll
  for (int f = 0; f < 12; ++f)
    qf[f] = *reinterpret_cast<const bf16x8*>(Qh + (size_t)q * DHc + f * 16 + hi * 8);

  bf16x8 kf[12];
#pragma unroll
  for (int f = 0; f < 12; ++f)
    kf[f] = *reinterpret_cast<const bf16x8*>(Kh + (size_t)l31 * DHc + f * 16 + hi * 8);

  f32x16 ot[4] = {};
  float m = -INFINITY, lsum = 0.f;

  auto softmax_pv = [&](const float* v, const bf16x8* vf) {
    float pmax = fmaxf(fmaxf(fmaxf(v[0], v[1]), fmaxf(v[2], v[3])),
                       fmaxf(fmaxf(v[4], v[5]), fmaxf(v[6], v[7])));
    float pmax2 = fmaxf(fmaxf(fmaxf(v[8], v[9]), fmaxf(v[10], v[11])),
                        fmaxf(fmaxf(v[12], v[13]), fmaxf(v[14], v[15])));
    pmax = fmaxf(pmax, pmax2);
    pmax = fmaxf(pmax, __shfl_xor(pmax, 32, 64));

    float cf = 1.f;
    if (!__all(pmax - m <= 8.0f)) {   // defer-max (log2 units): P bounded by 2^8
      const float mnew = fmaxf(m, pmax);
      cf = exp2f(m - mnew);
      m = mnew;
#pragma unroll
      for (int dt = 0; dt < 4; ++dt)
#pragma unroll
        for (int r = 0; r < 16; ++r) ot[dt][r] *= cf;
    }

    float p[16];
    float rs = 0.f;
#pragma unroll
    for (int r = 0; r < 16; ++r) { p[r] = exp2f(v[r] - m); rs += p[r]; }
    rs += __shfl_xor(rs, 32, 64);
    lsum = lsum * cf + rs;

    uint32_t c[8], x[8];
#pragma unroll
    for (int i = 0; i < 8; ++i) {
      asm("v_cvt_pk_bf16_f32 %0, %1, %2" : "=v"(c[i]) : "v"(p[2 * i]), "v"(p[2 * i + 1]));
      x[i] = (uint32_t)__shfl_xor((int)c[i], 32, 64);
    }
    union { uint32_t w[4]; bf16x8 v8; } pa0, pa1;
    pa0.w[0] = hi ? x[2] : c[0];
    pa0.w[1] = hi ? x[3] : c[1];
    pa0.w[2] = hi ? c[2] : x[0];
    pa0.w[3] = hi ? c[3] : x[1];
    pa1.w[0] = hi ? x[6] : c[4];
    pa1.w[1] = hi ? x[7] : c[5];
    pa1.w[2] = hi ? c[6] : x[4];
    pa1.w[3] = hi ? c[7] : x[5];

#pragma unroll
    for (int dt = 0; dt < 4; ++dt) {
      ot[dt] = __builtin_amdgcn_mfma_f32_32x32x16_bf16(vf[dt * 2], pa0.v8, ot[dt], 0, 0, 0);
      ot[dt] = __builtin_amdgcn_mfma_f32_32x32x16_bf16(vf[dt * 2 + 1], pa1.v8, ot[dt], 0, 0, 0);
    }
  };

  for (int kb = 0; kb < tl; ++kb) {
    const int kbase = kb * 32;
    bf16x8 vf[8];
#pragma unroll
    for (int dt = 0; dt < 4; ++dt)
#pragma unroll
      for (int k2 = 0; k2 < 2; ++k2)
        vf[dt * 2 + k2] = *reinterpret_cast<const bf16x8*>(
            Vh + (size_t)(dt * 32 + l31) * Sc + kbase + k2 * 16 + hi * 8);

    f32x16 s = {};
#pragma unroll
    for (int f = 0; f < 12; ++f)
      s = __builtin_amdgcn_mfma_f32_32x32x16_bf16(kf[f], qf[f], s, 0, 0, 0);

    // prefetch next K block (kb+1 <= tl always valid)
#pragma unroll
    for (int f = 0; f < 12; ++f)
      kf[f] = *reinterpret_cast<const bf16x8*>(Kh + (size_t)(kbase + 32 + l31) * DHc + f * 16 + hi * 8);

    float v[16];
#pragma unroll
    for (int r = 0; r < 16; ++r) v[r] = s[r];
    softmax_pv(v, vf);
  }

  {  // diagonal block (the only masked one)
    const int kbase = tl * 32;
    bf16x8 vf[8];
#pragma unroll
    for (int dt = 0; dt < 4; ++dt)
#pragma unroll
      for (int k2 = 0; k2 < 2; ++k2)
        vf[dt * 2 + k2] = *reinterpret_cast<const bf16x8*>(
            Vh + (size_t)(dt * 32 + l31) * Sc + kbase + k2 * 16 + hi * 8);

    f32x16 s = {};
#pragma unroll
    for (int f = 0; f < 12; ++f)
      s = __builtin_amdgcn_mfma_f32_32x32x16_bf16(kf[f], qf[f], s, 0, 0, 0);

    float v[16];
#pragma unroll
    for (int r = 0; r < 16; ++r) {
      const int kl = (r & 3) + 8 * (r >> 2) + 4 * hi;
      v[r] = (kl <= l31) ? s[r] : -3.0e38f;
    }
    softmax_pv(v, vf);
  }

  const float inv = 1.0f / lsum;
  unsigned short* dst = attnOut + ((size_t)(b * Sc + q)) * (Hc * DVc) + h * DVc;
#pragma unroll
  for (int dt = 0; dt < 4; ++dt)
#pragma unroll
    for (int rq = 0; rq < 4; ++rq) {
      uint32_t lo = (uint32_t)f2bf(ot[dt][rq * 4 + 0] * inv) |
                    ((uint32_t)f2bf(ot[dt][rq * 4 + 1] * inv) << 16);
      uint32_t hi2 = (uint32_t)f2bf(ot[dt][rq * 4 + 2] * inv) |
                     ((uint32_t)f2bf(ot[dt][rq * 4 + 3] * inv) << 16);
      uint2 pk; pk.x = lo; pk.y = hi2;
      *reinterpret_cast<uint2*>(dst + dt * 32 + 8 * rq + 4 * hi) = pk;
    }
}

// ---------------- host launch ----------------
extern "C" void kernel_launch(void* const* d_in, const int* in_sizes, int n_in,
                              void* d_out, int out_size, void* d_ws, size_t ws_size,
                              hipStream_t stream) {
  (void)in_sizes; (void)n_in; (void)out_size; (void)ws_size;
  const float* hidden = (const float*)d_in[0];
  const float* w_qa  = (const float*)d_in[2];
  const float* b_qa  = (const float*)d_in[3];
  const float* g_q   = (const float*)d_in[4];
  const float* w_qb  = (const float*)d_in[5];
  const float* b_qb  = (const float*)d_in[6];
  const float* w_kva = (const float*)d_in[7];
  const float* b_kva = (const float*)d_in[8];
  const float* g_kv  = (const float*)d_in[9];
  const float* w_kvb = (const float*)d_in[10];
  const float* b_kvb = (const float*)d_in[11];
  const float* w_o   = (const float*)d_in[12];
  const float* b_o   = (const float*)d_in[13];
  float* out = (float*)d_out;

  char* ws = (char*)d_ws;
  size_t off = 0;
  auto alloc = [&](size_t bytes) -> void* {
    void* p = ws + off;
    off += (bytes + 255) & ~(size_t)255;
    return p;
  };
  const int MS = Bc * Sc;  // 4096 rows

  unsigned short* Xbf   = (unsigned short*)alloc((size_t)MS * Dc * 2);
  unsigned short* WqaT  = (unsigned short*)alloc((size_t)RQc * Dc * 2);
  unsigned short* WqbT  = (unsigned short*)alloc((size_t)Hc * DHc * RQc * 2);
  unsigned short* WkvaT = (unsigned short*)alloc((size_t)(RKVc + DRc) * Dc * 2);
  unsigned short* WkvbT = (unsigned short*)alloc((size_t)HKVc * 256 * RKVc * 2);
  unsigned short* WoT   = (unsigned short*)alloc((size_t)Dc * Hc * DVc * 2);
  float* cosT = (float*)alloc((size_t)Sc * DRc * 4);
  float* sinT = (float*)alloc((size_t)Sc * DRc * 4);
  float* qa   = (float*)alloc((size_t)MS * RQc * 4);
  unsigned short* qan  = (unsigned short*)alloc((size_t)MS * RQc * 2);
  unsigned short* qb   = (unsigned short*)alloc((size_t)MS * Hc * DHc * 2);
  float* kva  = (float*)alloc((size_t)MS * (RKVc + DRc) * 4);
  unsigned short* kvcn = (unsigned short*)alloc((size_t)MS * RKVc * 2);
  unsigned short* kvb  = (unsigned short*)alloc((size_t)MS * HKVc * 256 * 2);
  unsigned short* Qt   = (unsigned short*)alloc((size_t)Bc * Hc * Sc * DHc * 2);
  unsigned short* Kt   = (unsigned short*)alloc((size_t)Bc * HKVc * Sc * DHc * 2);
  unsigned short* Vt   = (unsigned short*)alloc((size_t)Bc * HKVc * DVc * Sc * 2);
  unsigned short* attnb= (unsigned short*)alloc((size_t)MS * Hc * DVc * 2);

  f2b_kernel<<<dim3(512), dim3(256), 0, stream>>>(hidden, Xbf, MS * Dc);
  // weight transposes: in[K][N] f32 -> out[N][K] bf16
  wtrans_kernel<<<dim3(RQc / 32, Dc / 32), 256, 0, stream>>>(w_qa, WqaT, Dc, RQc);
  wtrans_kernel<<<dim3(Hc * DHc / 32, RQc / 32), 256, 0, stream>>>(w_qb, WqbT, RQc, Hc * DHc);
  wtrans_kernel<<<dim3((RKVc + DRc) / 32, Dc / 32), 256, 0, stream>>>(w_kva, WkvaT, Dc, RKVc + DRc);
  wtrans_kernel<<<dim3(HKVc * 256 / 32, RKVc / 32), 256, 0, stream>>>(w_kvb, WkvbT, RKVc, HKVc * 256);
  wtrans_kernel<<<dim3(Dc / 32, Hc * DVc / 32), 256, 0, stream>>>(w_o, WoT, Hc * DVc, Dc);
  rope_table_kernel<<<dim3(512), dim3(256), 0, stream>>>(cosT, sinT);

  gemm_tn_kernel<false, false><<<dim3(RQc / 128, MS / 128), 256, 0, stream>>>(Xbf, WqaT, b_qa, qa, MS, RQc, Dc);
  rmsnorm_kernel<1024><<<dim3(MS), 256, 0, stream>>>(qa, RQc, g_q, qan);
  gemm_tn_kernel<true, false><<<dim3(Hc * DHc / 128, MS / 128), 256, 0, stream>>>(qan, WqbT, b_qb, qb, MS, Hc * DHc, RQc);
  gemm_tn_kernel<false, true><<<dim3((RKVc + DRc + 127) / 128, MS / 128), 256, 0, stream>>>(Xbf, WkvaT, b_kva, kva, MS, RKVc + DRc, Dc);
  rmsnorm_kernel<512><<<dim3(MS), 256, 0, stream>>>(kva, RKVc + DRc, g_kv, kvcn);
  gemm_tn_kernel<true, false><<<dim3(HKVc * 256 / 128, MS / 128), 256, 0, stream>>>(kvcn, WkvbT, b_kvb, kvb, MS, HKVc * 256, RKVc);

  prep_q_kernel<<<dim3(MS), 256, 0, stream>>>(qb, cosT, sinT, Qt);
  prep_k_kernel<<<dim3(MS), 256, 0, stream>>>(kvb, kva, cosT, sinT, Kt);
  vtrans_kernel<<<dim3(Bc * HKVc * (Sc / 32) * (DVc / 32)), 256, 0, stream>>>(kvb, Vt);

  attn_kernel<<<dim3(2048), dim3(64), 0, stream>>>(Qt, Kt, Vt, attnb);

  gemm_tn_kernel<false, false><<<dim3(Dc / 128, MS / 128), 256, 0, stream>>>(attnb, WoT, b_o, out, MS, Dc, Hc * DVc);
}